// Round 7
// baseline (124.315 us; speedup 1.0000x reference)
//
#include <hip/hip_runtime.h>
#include <math.h>

#define CUTOFF_F 5.0f
#define MIN_DIST_F 0.01f
#define EPS_D 1e-7

typedef float f32x4 __attribute__((ext_vector_type(4)));

// ---------------------------------------------------------------------------
// Prep: per-system 3x3 inverse (double), wrapped positions, cartesian shifts.
// wp[b*N+n][3] (f32), sc[b*27+s][3] (f32) into workspace.
// ---------------------------------------------------------------------------
__global__ void bnl_prep(const float* __restrict__ pos,
                         const float* __restrict__ cell,
                         float* __restrict__ wp,
                         float* __restrict__ sc,
                         int B, int N) {
    int tid = blockIdx.x * blockDim.x + threadIdx.x;
    int nthreads = gridDim.x * blockDim.x;

    for (int t = tid; t < B * 27; t += nthreads) {
        int b = t / 27, s = t - b * 27;
        int sx = s / 9 - 1;
        int sy = (s / 3) % 3 - 1;
        int sz = s - (s / 3) * 3 - 1;
        const float* c = cell + b * 9;
        sc[t * 3 + 0] = (float)((double)sx * c[0] + (double)sy * c[3] + (double)sz * c[6]);
        sc[t * 3 + 1] = (float)((double)sx * c[1] + (double)sy * c[4] + (double)sz * c[7]);
        sc[t * 3 + 2] = (float)((double)sx * c[2] + (double)sy * c[5] + (double)sz * c[8]);
    }

    int total = B * N;
    for (int n = tid; n < total; n += nthreads) {
        int b = n / N;
        const float* c = cell + b * 9;
        double a00 = c[0], a01 = c[1], a02 = c[2];
        double a10 = c[3], a11 = c[4], a12 = c[5];
        double a20 = c[6], a21 = c[7], a22 = c[8];
        double co00 =  (a11 * a22 - a12 * a21);
        double co01 = -(a10 * a22 - a12 * a20);
        double co02 =  (a10 * a21 - a11 * a20);
        double det = a00 * co00 + a01 * co01 + a02 * co02;
        double id = 1.0 / det;
        double m00 = co00 * id;
        double m01 = -(a01 * a22 - a02 * a21) * id;
        double m02 =  (a01 * a12 - a02 * a11) * id;
        double m10 = co01 * id;
        double m11 =  (a00 * a22 - a02 * a20) * id;
        double m12 = -(a00 * a12 - a02 * a10) * id;
        double m20 = co02 * id;
        double m21 = -(a00 * a21 - a01 * a20) * id;
        double m22 =  (a00 * a11 - a01 * a10) * id;

        double p0 = pos[n * 3 + 0], p1 = pos[n * 3 + 1], p2 = pos[n * 3 + 2];
        double s0 = p0 * m00 + p1 * m10 + p2 * m20 + EPS_D;
        double s1 = p0 * m01 + p1 * m11 + p2 * m21 + EPS_D;
        double s2 = p0 * m02 + p1 * m12 + p2 * m22 + EPS_D;
        s0 -= floor(s0); s1 -= floor(s1); s2 -= floor(s2);
        s0 -= EPS_D; s1 -= EPS_D; s2 -= EPS_D;
        wp[n * 3 + 0] = (float)(s0 * a00 + s1 * a10 + s2 * a20);
        wp[n * 3 + 1] = (float)(s0 * a01 + s1 * a11 + s2 * a21);
        wp[n * 3 + 2] = (float)(s0 * a02 + s1 * a12 + s2 * a22);
    }
}

// ---------------------------------------------------------------------------
// Fill (round-2 structure + XCD-chunk swizzle + 2-quad store bursts).
// Block = (b,i) full row; stage wp[b] + sc[b] in LDS; no mid-loop barrier.
// Each thread-iteration computes TWO independent quads (8 pairs), then issues
// a burst of 10 independent float4 stores. Plain cached stores.
// Output: [diff 3*D1][dist D1][mask D1], D1 = B*N*N*27.
// ---------------------------------------------------------------------------
__global__ __launch_bounds__(256) void bnl_fill5(const float* __restrict__ wp,
                                                 const float* __restrict__ sc,
                                                 float* __restrict__ out,
                                                 int B, int N) {
    extern __shared__ float lds[];          // [N*3] wp row, then [81] sc
    float* lwp = lds;
    float* lsc = lds + N * 3;

    // XCD-chunk swizzle: grid = B*N; give each XCD one contiguous chunk.
    int nwg = gridDim.x;
    int blk = blockIdx.x;
    if ((nwg & 7) == 0) {
        int chunk = nwg >> 3;
        blk = (blk & 7) * chunk + (blk >> 3);
    }
    int b = blk / N;
    int i = blk - b * N;

    const float* wrow = wp + (size_t)b * N * 3;
    int nf4 = (N * 3) >> 2;
    for (int t = threadIdx.x; t < nf4; t += blockDim.x)
        reinterpret_cast<f32x4*>(lwp)[t] = reinterpret_cast<const f32x4*>(wrow)[t];
    for (int t = (nf4 << 2) + threadIdx.x; t < N * 3; t += blockDim.x)
        lwp[t] = wrow[t];
    for (int t = threadIdx.x; t < 81; t += blockDim.x)
        lsc[t] = sc[(size_t)b * 81 + t];
    __syncthreads();

    float pix = lwp[i * 3 + 0];
    float piy = lwp[i * 3 + 1];
    float piz = lwp[i * 3 + 2];

    size_t D1  = (size_t)B * N * N * 27;
    size_t row = (size_t)(b * N + i) * N * 27;
    float* diff_out = out + row * 3;
    float* dist_out = out + 3 * D1 + row;
    float* mask_out = out + 4 * D1 + row;

    int NQ = (N * 27) >> 2;                 // quads per row
    int BD = blockDim.x;

    // two quads per iteration: qA = q0+t, qB = q0+BD+t
    for (int q0 = 0; q0 < NQ; q0 += 2 * BD) {
        float dvA[12], tvA[4], mvA[4];
        float dvB[12], tvB[4], mvB[4];
        int qA = q0 + threadIdx.x;
        int qB = qA + BD;
        bool hasA = qA < NQ;
        bool hasB = qB < NQ;

        if (hasA) {
            int p0 = qA << 2;
            unsigned j = (unsigned)p0 / 27u;
            unsigned s = (unsigned)p0 - j * 27u;
#pragma unroll
            for (int k = 0; k < 4; ++k) {
                float dx = lwp[j * 3 + 0] + lsc[s * 3 + 0] - pix;
                float dy = lwp[j * 3 + 1] + lsc[s * 3 + 1] - piy;
                float dz = lwp[j * 3 + 2] + lsc[s * 3 + 2] - piz;
                float dist = sqrtf(dx * dx + dy * dy + dz * dz);
                bool m = (dist < CUTOFF_F) && (dist > MIN_DIST_F);
                dvA[k * 3 + 0] = m ? dx : 0.0f;
                dvA[k * 3 + 1] = m ? dy : 0.0f;
                dvA[k * 3 + 2] = m ? dz : 0.0f;
                tvA[k] = m ? dist : 0.0f;
                mvA[k] = m ? 1.0f : 0.0f;
                ++s;
                if (s == 27u) { s = 0u; ++j; }
            }
        }
        if (hasB) {
            int p0 = qB << 2;
            unsigned j = (unsigned)p0 / 27u;
            unsigned s = (unsigned)p0 - j * 27u;
#pragma unroll
            for (int k = 0; k < 4; ++k) {
                float dx = lwp[j * 3 + 0] + lsc[s * 3 + 0] - pix;
                float dy = lwp[j * 3 + 1] + lsc[s * 3 + 1] - piy;
                float dz = lwp[j * 3 + 2] + lsc[s * 3 + 2] - piz;
                float dist = sqrtf(dx * dx + dy * dy + dz * dz);
                bool m = (dist < CUTOFF_F) && (dist > MIN_DIST_F);
                dvB[k * 3 + 0] = m ? dx : 0.0f;
                dvB[k * 3 + 1] = m ? dy : 0.0f;
                dvB[k * 3 + 2] = m ? dz : 0.0f;
                tvB[k] = m ? dist : 0.0f;
                mvB[k] = m ? 1.0f : 0.0f;
                ++s;
                if (s == 27u) { s = 0u; ++j; }
            }
        }
        // store burst: 10 independent float4 stores
        if (hasA) {
            f32x4* dp = reinterpret_cast<f32x4*>(diff_out + (size_t)(qA << 2) * 3);
            dp[0] = (f32x4){dvA[0], dvA[1], dvA[2],  dvA[3]};
            dp[1] = (f32x4){dvA[4], dvA[5], dvA[6],  dvA[7]};
            dp[2] = (f32x4){dvA[8], dvA[9], dvA[10], dvA[11]};
            *reinterpret_cast<f32x4*>(dist_out + ((size_t)qA << 2)) = (f32x4){tvA[0], tvA[1], tvA[2], tvA[3]};
            *reinterpret_cast<f32x4*>(mask_out + ((size_t)qA << 2)) = (f32x4){mvA[0], mvA[1], mvA[2], mvA[3]};
        }
        if (hasB) {
            f32x4* dp = reinterpret_cast<f32x4*>(diff_out + (size_t)(qB << 2) * 3);
            dp[0] = (f32x4){dvB[0], dvB[1], dvB[2],  dvB[3]};
            dp[1] = (f32x4){dvB[4], dvB[5], dvB[6],  dvB[7]};
            dp[2] = (f32x4){dvB[8], dvB[9], dvB[10], dvB[11]};
            *reinterpret_cast<f32x4*>(dist_out + ((size_t)qB << 2)) = (f32x4){tvB[0], tvB[1], tvB[2], tvB[3]};
            *reinterpret_cast<f32x4*>(mask_out + ((size_t)qB << 2)) = (f32x4){mvB[0], mvB[1], mvB[2], mvB[3]};
        }
    }
}

extern "C" void kernel_launch(void* const* d_in, const int* in_sizes, int n_in,
                              void* d_out, int out_size, void* d_ws, size_t ws_size,
                              hipStream_t stream) {
    const float* pos  = (const float*)d_in[0];   // [B*N,3]
    const float* cell = (const float*)d_in[1];   // [B,3,3]
    int B = in_sizes[1] / 9;
    int N = in_sizes[0] / (3 * B);

    float* wp = (float*)d_ws;                    // B*N*3 floats
    float* sc = wp + (size_t)B * N * 3;          // B*27*3 floats

    bnl_prep<<<32, 256, 0, stream>>>(pos, cell, wp, sc, B, N);

    size_t lds_bytes = ((size_t)N * 3 + 81) * sizeof(float);
    bnl_fill5<<<B * N, 256, lds_bytes, stream>>>(wp, sc, (float*)d_out, B, N);
}